// Round 11
// baseline (20137.875 us; speedup 1.0000x reference)
//
#include <hip/hip_runtime.h>

#define T_STEPS 1024
#define BATCH   256
#define DIM     128
#define HID     256
#define BT      16
#define NBLK    (BATCH / BT)   // 16 blocks, one per batch tile; no inter-block comm

// LDS layout (bytes)
#define WD_OFF 0          // [256][256] bf16, swizzled  = 131072
#define H_OFF  131072     // [16][256]  bf16, swizzled  = 8192
#define C_OFF  139264     // [16][256]  bf16, swizzled  = 8192
#define X_OFF  147456     // [2][16][128] bf16, swizzled = 8192 (double-buffered)
#define SMEM_TOTAL 155648 // 152 KiB <= 160 KiB

typedef float f32x4 __attribute__((ext_vector_type(4)));
typedef short bf16x8 __attribute__((ext_vector_type(8)));

__device__ __forceinline__ unsigned short f2bf(float f) {
    union { float f; unsigned u; } v; v.f = f;
    unsigned r = (v.u + 0x7fffu + ((v.u >> 16) & 1u)) >> 16;   // RNE
    return (unsigned short)r;
}
__device__ __forceinline__ bf16x8 cvt8(float4 a, float4 b) {
    bf16x8 r;
    r[0] = (short)f2bf(a.x); r[1] = (short)f2bf(a.y);
    r[2] = (short)f2bf(a.z); r[3] = (short)f2bf(a.w);
    r[4] = (short)f2bf(b.x); r[5] = (short)f2bf(b.y);
    r[6] = (short)f2bf(b.z); r[7] = (short)f2bf(b.w);
    return r;
}
__device__ __forceinline__ float sigm(float v) { return 1.0f / (1.0f + __expf(-v)); }
__device__ __forceinline__ float tanh_fast(float v) {
    const float e = __expf(2.0f * v);
    return 1.0f - 2.0f / (e + 1.0f);
}
// lgkm-only barrier: orders LDS across waves; vmem (x prefetch / out stores) floats.
__device__ __forceinline__ void lgkm_bar() {
    asm volatile("s_waitcnt lgkmcnt(0)" ::: "memory");
    __builtin_amdgcn_s_barrier();
    __builtin_amdgcn_sched_barrier(0);
}

__global__ __launch_bounds__(512, 1)
void tlstm_kernel(const float* __restrict__ x,
                  const float* __restrict__ dts,
                  const float* __restrict__ h0,
                  const float* __restrict__ c0,
                  const float* __restrict__ W,
                  const float* __restrict__ U,
                  const float* __restrict__ bvec,
                  const float* __restrict__ Wd,
                  const float* __restrict__ bd,
                  float* __restrict__ out)
{
    extern __shared__ char smem[];
    const int tid  = threadIdx.x;
    const int lane = tid & 63;
    const int w    = tid >> 6;      // wave 0..7: owns h-cols [w*32, w*32+32)
    const int lrow = lane & 15;     // A-row(batch) / D-col(weight row)
    const int lkg  = lane >> 4;     // K-group / D row-group
    const int bb   = blockIdx.x * BT;

    // ---- one-time: Wd -> LDS (bf16, XOR-swizzled: byte ^= (row&7)<<4) ----
    for (int idx = tid; idx < 256 * 256; idx += 512) {
        const int r = idx >> 8, k = idx & 255;
        int bo = (r << 9) + (k << 1); bo ^= (r & 7) << 4;
        *(unsigned short*)(smem + WD_OFF + bo) = f2bf(Wd[(size_t)r * HID + k]);
    }
    // ---- h0/c0 -> LDS tiles ----
    for (int idx = tid; idx < 16 * 256; idx += 512) {
        const int r = idx >> 8, k = idx & 255;
        int bo = (r << 9) + (k << 1); bo ^= (r & 7) << 4;
        *(unsigned short*)(smem + H_OFF + bo) = f2bf(h0[(size_t)(bb + r) * HID + k]);
        *(unsigned short*)(smem + C_OFF + bo) = f2bf(c0[(size_t)(bb + r) * HID + k]);
    }
    // ---- x(0) -> LDS x-tile buf0 (each thread: 4 f32 -> 4 bf16) ----
    {
        const int r = tid >> 5, c4 = (tid & 31) * 4;
        const float4 f = *(const float4*)(x + ((size_t)0 * BATCH + bb + r) * DIM + c4);
        const unsigned long long pk =
              (unsigned long long)f2bf(f.x)
            | ((unsigned long long)f2bf(f.y) << 16)
            | ((unsigned long long)f2bf(f.z) << 32)
            | ((unsigned long long)f2bf(f.w) << 48);
        int bo = (r << 8) + (c4 << 1); bo ^= (r & 7) << 4;
        *(unsigned long long*)(smem + X_OFF + bo) = pk;
    }

    // ---- persistent weight fragments in VGPRs (statically indexed) ----
    // UB[nt][kc]: gate q=nt>>1, col-half hf=nt&1; row = q*HID + w*32 + hf*16 + lrow
    bf16x8 UB[8][8];
    bf16x8 WB[8][4];
    #pragma unroll
    for (int nt = 0; nt < 8; ++nt) {
        const int q = nt >> 1, hf = nt & 1;
        const int grow = q * HID + w * 32 + hf * 16 + lrow;
        #pragma unroll
        for (int kc = 0; kc < 8; ++kc) {
            const float* up = U + (size_t)grow * HID + kc * 32 + lkg * 8;
            UB[nt][kc] = cvt8(*(const float4*)up, *(const float4*)(up + 4));
        }
        #pragma unroll
        for (int kc = 0; kc < 4; ++kc) {
            const float* wp = W + (size_t)grow * DIM + kc * 32 + lkg * 8;
            WB[nt][kc] = cvt8(*(const float4*)wp, *(const float4*)(wp + 4));
        }
    }

    // ---- per-lane constants: biases for the 2 owned cols ----
    float bI[2], bF[2], bG[2], bO[2], bD2[2];
    #pragma unroll
    for (int hf = 0; hf < 2; ++hf) {
        const int j = w * 32 + hf * 16 + lrow;
        bI[hf]  = bvec[j];
        bF[hf]  = bvec[HID + j];
        bG[hf]  = bvec[2 * HID + j];
        bO[hf]  = bvec[3 * HID + j];
        bD2[hf] = bd[j];
    }

    // ---- c in f32 registers: lane holds c for rows lkg*4+i, cols w*32+hf*16+lrow ----
    float c_reg[2][4];
    #pragma unroll
    for (int hf = 0; hf < 2; ++hf)
        #pragma unroll
        for (int i = 0; i < 4; ++i)
            c_reg[hf][i] = c0[(size_t)(bb + lkg * 4 + i) * HID + w * 32 + hf * 16 + lrow];

    float dt_r[4], dt_n[4];
    #pragma unroll
    for (int i = 0; i < 4; ++i)
        dt_r[i] = dts[(size_t)(bb + lkg * 4 + i) * T_STEPS + 0];

    __syncthreads();   // weights + tiles staged

    float4 xpre;   // raw x(t+1) prefetch (4 f32/thread)

    #pragma unroll 1
    for (int t = 0; t < T_STEPS; ++t) {
        const int xb = t & 1;

        // ---- issue x(t+1)/dt(t+1) loads early: latency hides under MFMA phase ----
        const int tn = (t + 1 < T_STEPS) ? t + 1 : t;
        {
            const int r = tid >> 5, c4 = (tid & 31) * 4;
            xpre = *(const float4*)(x + ((size_t)tn * BATCH + bb + r) * DIM + c4);
            #pragma unroll
            for (int i = 0; i < 4; ++i)
                dt_n[i] = dts[(size_t)(bb + lkg * 4 + i) * T_STEPS + tn];
        }

        // ---- MFMA phase: gates (x@W^T + h@U^T) and Cs (c@Wd^T) ----
        f32x4 accG[4][2];
        f32x4 accC[2];
        #pragma unroll
        for (int q = 0; q < 4; ++q)
            #pragma unroll
            for (int hf = 0; hf < 2; ++hf)
                accG[q][hf] = (f32x4){0.f, 0.f, 0.f, 0.f};
        accC[0] = (f32x4){0.f, 0.f, 0.f, 0.f};
        accC[1] = (f32x4){0.f, 0.f, 0.f, 0.f};

        #pragma unroll
        for (int kc = 0; kc < 4; ++kc) {           // x part, K=128
            int bo = (lrow << 8) + ((kc * 32 + lkg * 8) << 1); bo ^= (lrow & 7) << 4;
            const bf16x8 xa = *(const bf16x8*)(smem + X_OFF + xb * 4096 + bo);
            #pragma unroll
            for (int q = 0; q < 4; ++q)
                #pragma unroll
                for (int hf = 0; hf < 2; ++hf)
                    accG[q][hf] = __builtin_amdgcn_mfma_f32_16x16x32_bf16(
                        xa, WB[q * 2 + hf][kc], accG[q][hf], 0, 0, 0);
        }
        #pragma unroll
        for (int kc = 0; kc < 8; ++kc) {           // h part, K=256
            int bo = (lrow << 9) + ((kc * 32 + lkg * 8) << 1); bo ^= (lrow & 7) << 4;
            const bf16x8 ha = *(const bf16x8*)(smem + H_OFF + bo);
            #pragma unroll
            for (int q = 0; q < 4; ++q)
                #pragma unroll
                for (int hf = 0; hf < 2; ++hf)
                    accG[q][hf] = __builtin_amdgcn_mfma_f32_16x16x32_bf16(
                        ha, UB[q * 2 + hf][kc], accG[q][hf], 0, 0, 0);
        }
        #pragma unroll
        for (int kc = 0; kc < 8; ++kc) {           // Cs part, K=256
            int bo = (lrow << 9) + ((kc * 32 + lkg * 8) << 1); bo ^= (lrow & 7) << 4;
            const bf16x8 ca = *(const bf16x8*)(smem + C_OFF + bo);
            #pragma unroll
            for (int hf = 0; hf < 2; ++hf) {
                const int wr = w * 32 + hf * 16 + lrow;
                int wo = (wr << 9) + ((kc * 32 + lkg * 8) << 1); wo ^= (wr & 7) << 4;
                const bf16x8 wd = *(const bf16x8*)(smem + WD_OFF + wo);
                accC[hf] = __builtin_amdgcn_mfma_f32_16x16x32_bf16(ca, wd, accC[hf], 0, 0, 0);
            }
        }
        lgkm_bar();   // #1: all reads of h(t), c(t), x(t) complete

        // ---- stage x(t+1) into the other x buffer (raw reg -> bf16 -> LDS) ----
        {
            const int r = tid >> 5, c4 = (tid & 31) * 4;
            const unsigned long long pk =
                  (unsigned long long)f2bf(xpre.x)
                | ((unsigned long long)f2bf(xpre.y) << 16)
                | ((unsigned long long)f2bf(xpre.z) << 32)
                | ((unsigned long long)f2bf(xpre.w) << 48);
            int bo = (r << 8) + (c4 << 1); bo ^= (r & 7) << 4;
            *(unsigned long long*)(smem + X_OFF + (xb ^ 1) * 4096 + bo) = pk;
        }

        // ---- elementwise T-LSTM update, fully in-register ----
        float gdt[4];
        #pragma unroll
        for (int i = 0; i < 4; ++i)
            gdt[i] = 1.0f / __logf(2.718281828459045f + dt_r[i]);

        #pragma unroll
        for (int hf = 0; hf < 2; ++hf) {
            const int j = w * 32 + hf * 16 + lrow;
            #pragma unroll
            for (int i = 0; i < 4; ++i) {
                const int rb = lkg * 4 + i;
                const float ipre = accG[0][hf][i] + bI[hf];
                const float fpre = accG[1][hf][i] + bF[hf];
                const float gpre = accG[2][hf][i] + bG[hf];
                const float opre = accG[3][hf][i] + bO[hf];
                const float Cs    = tanh_fast(accC[hf][i] + bD2[hf]);
                const float cstar = c_reg[hf][i] - Cs + Cs * gdt[i];
                const float cn = sigm(fpre) * cstar + sigm(ipre) * tanh_fast(gpre);
                const float hn = sigm(opre) * tanh_fast(cn);
                c_reg[hf][i] = cn;

                // write h(t+1), c(t+1) into LDS tiles (bf16, swizzled)
                int bo = (rb << 9) + (j << 1); bo ^= (rb & 7) << 4;
                *(unsigned short*)(smem + H_OFF + bo) = f2bf(hn);
                *(unsigned short*)(smem + C_OFF + bo) = f2bf(cn);

                // output store (fire-and-forget)
                out[((size_t)t * BATCH + bb + rb) * HID + j] = hn;
                if (t == T_STEPS - 1) {
                    const size_t base = (size_t)T_STEPS * BATCH * HID;
                    out[base + (size_t)(bb + rb) * HID + j] = hn;
                    out[base + (size_t)BATCH * HID + (size_t)(bb + rb) * HID + j] = cn;
                }
            }
        }
        #pragma unroll
        for (int i = 0; i < 4; ++i) dt_r[i] = dt_n[i];

        lgkm_bar();   // #2: h/c/x writes visible to all waves before next reads
    }
}

extern "C" void kernel_launch(void* const* d_in, const int* in_sizes, int n_in,
                              void* d_out, int out_size, void* d_ws, size_t ws_size,
                              hipStream_t stream) {
    (void)in_sizes; (void)n_in; (void)out_size; (void)d_ws; (void)ws_size;
    const float* x   = (const float*)d_in[0];
    const float* dts = (const float*)d_in[1];
    const float* h0  = (const float*)d_in[2];
    const float* c0  = (const float*)d_in[3];
    const float* W   = (const float*)d_in[4];
    const float* U   = (const float*)d_in[5];
    const float* bv  = (const float*)d_in[6];
    const float* Wd  = (const float*)d_in[7];
    const float* bd  = (const float*)d_in[8];
    float* out = (float*)d_out;

    hipFuncSetAttribute((const void*)tlstm_kernel,
                        hipFuncAttributeMaxDynamicSharedMemorySize, SMEM_TOTAL);
    tlstm_kernel<<<dim3(NBLK), dim3(512), SMEM_TOTAL, stream>>>(
        x, dts, h0, c0, W, U, bv, Wd, bd, out);
}